// Round 5
// baseline (107.440 us; speedup 1.0000x reference)
//
#include <hip/hip_runtime.h>
#include <hip/hip_cooperative_groups.h>

namespace cg = cooperative_groups;

// GAT layer, B=4, N=256, IN=128, H=4, D=64 — single cooperative kernel (R12).
//
// out = att @ (h@W)slice.  Phase 1 (prep): Wh^T bf16 + f1/f2 attention
// vectors. cg grid sync. Phase 2 (attn): masked softmax + one K=256 MFMA GEMM
// per (b,hp,32-row tile); softmax denominator computed by MFMA against a
// ones-fragment (rowsum lands per-lane in exactly the accumulator layout the
// output needs — no shfl chain, no sinv LDS round-trip).
//
// R5 changes vs R4 (launch-gap + serial-tail diet):
//  - two kernels -> ONE hipLaunchCooperativeKernel (kills a dispatch gap).
//  - softmax row-sum via 8 extra MFMAs (B = ones) instead of a 6-level
//    __shfl_xor chain per row; denominator now sums the same bf16-rounded
//    attb the numerator GEMM uses (more self-consistent).
//  - prep issues ALL global loads (W, h, a) before any dependent work.
//
// Index algebra (harness-verified R0/R3/R4):
//   e[b,hp,i,j] = lrelu_0.2( f1flat[hp*256+i] + f2flat[(i&3)*256+j] )
//   att = softmax_j(adj==0 ? -inf : e);  out = (attU @ Wh[:,hp*64:+64]) / rowsum
//   no max-subtraction needed: |e| small, exp(-1e30)=0 exactly (R4-verified).

typedef __attribute__((ext_vector_type(8))) short bf16x8;
typedef __attribute__((ext_vector_type(4))) float f32x4;

__device__ __forceinline__ short bf1(float x) {
  unsigned u = __builtin_bit_cast(unsigned, x);
  u = (u + 0x7FFFu + ((u >> 16) & 1u)) >> 16;        // RNE, harness-verified
  return (short)u;
}
__device__ __forceinline__ bf16x8 pack8(float4 a, float4 b) {
  bf16x8 r;
  r[0]=bf1(a.x); r[1]=bf1(a.y); r[2]=bf1(a.z); r[3]=bf1(a.w);
  r[4]=bf1(b.x); r[5]=bf1(b.y); r[6]=bf1(b.z); r[7]=bf1(b.w);
  return r;
}

__global__ __launch_bounds__(512) void gat_all(
    const float* __restrict__ h, const float* __restrict__ W,
    const float* __restrict__ a, const int* __restrict__ adj,
    short* __restrict__ WhT, float* __restrict__ f1g, float* __restrict__ f2g,
    float* __restrict__ out)
{
  const int tid  = threadIdx.x;
  const int lane = tid & 63;
  const int quad = lane >> 4, col = lane & 15;
  const int wv   = tid >> 6;
  const int blk  = blockIdx.x;

  __shared__ short WbT[64][136];     // phase 1: bf16 W[:, nt*64:+64]^T : [c][k]
  __shared__ float f1p[32][4];       // phase 1: per-row partial dots, by tc
  __shared__ float f2p[32][4];
  __shared__ short attb[32][264];    // phase 2: bf16 unnormalized softmax rows

  // ================= phase 1: prep (blk -> b, nt, ms) ======================
  {
    const int ms = blk & 7, nt = (blk >> 3) & 3, b = blk >> 5;
    const int tc = wv & 3;                         // col-tile 0..3
    const int tr = wv >> 2;                        // row-tile 0..1

    // ---- issue ALL global loads first (cold HBM latency overlaps below) ---
    float4 wl[4];
#pragma unroll
    for (int q = 0; q < 4; q++) {
      const int idx = q * 512 + tid;               // 2048 float4 of W slice
      const int k = idx >> 4, c4 = idx & 15;
      wl[q] = *(const float4*)(W + k * 256 + nt * 64 + c4 * 4);
    }
    const float* hrow = h + (b*256 + ms*32 + tr*16 + col) * 128 + quad*8;
    float4 hv[8];
#pragma unroll
    for (int kk = 0; kk < 4; kk++) {
      hv[2*kk]   = *(const float4*)(hrow + kk*32);
      hv[2*kk+1] = *(const float4*)(hrow + kk*32 + 4);
    }
    const float a1v = a[tc*16 + col];
    const float a2v = a[64 + tc*16 + col];

    // ---- stage WbT ---------------------------------------------------------
#pragma unroll
    for (int q = 0; q < 4; q++) {
      const int idx = q * 512 + tid;
      const int k = idx >> 4, c4 = idx & 15;
      WbT[c4*4 + 0][k] = bf1(wl[q].x);
      WbT[c4*4 + 1][k] = bf1(wl[q].y);
      WbT[c4*4 + 2][k] = bf1(wl[q].z);
      WbT[c4*4 + 3][k] = bf1(wl[q].w);
    }
    __syncthreads();

    // ---- MFMA: Wh tile (16x16), K=128 -------------------------------------
    f32x4 acc = {0.f, 0.f, 0.f, 0.f};
#pragma unroll
    for (int kk = 0; kk < 4; kk++) {
      bf16x8 bw = *(const bf16x8*)&WbT[tc*16 + col][kk*32 + quad*8];
      acc = __builtin_amdgcn_mfma_f32_16x16x32_bf16(pack8(hv[2*kk], hv[2*kk+1]), bw, acc, 0, 0, 0);
    }
    // acc[r] = Wh[b][ms*32+tr*16+quad*4+r][nt*64+tc*16+col]
    {
      const int dcol = nt*64 + tc*16 + col;
      const int n0   = ms*32 + tr*16 + quad*4;
      int2 pk;
      pk.x = (int)((unsigned)(unsigned short)bf1(acc[0]) |
                   ((unsigned)(unsigned short)bf1(acc[1]) << 16));
      pk.y = (int)((unsigned)(unsigned short)bf1(acc[2]) |
                   ((unsigned)(unsigned short)bf1(acc[3]) << 16));
      *(int2*)(WhT + b*65536 + dcol*256 + n0) = pk;
    }
    // ---- f1/f2 partials: reduce acc[r]*a over this 16-col tile ------------
#pragma unroll
    for (int r = 0; r < 4; r++) {
      float v1 = acc[r] * a1v;
      float v2 = acc[r] * a2v;
#pragma unroll
      for (int off = 1; off < 16; off <<= 1) {
        v1 += __shfl_xor(v1, off, 64);
        v2 += __shfl_xor(v2, off, 64);
      }
      if (col == 0) {
        const int row = tr*16 + quad*4 + r;        // 0..31 within strip
        f1p[row][tc] = v1;
        f2p[row][tc] = v2;
      }
    }
    __syncthreads();

    // finalize: sum the 4 tc partials, write f{1,2}flat[b][(ms*32+n)*4 + nt]
    if (tid < 32) {
      const float s = f1p[tid][0] + f1p[tid][1] + f1p[tid][2] + f1p[tid][3];
      f1g[b*1024 + (ms*32 + tid)*4 + nt] = s;
    } else if (tid >= 64 && tid < 96) {
      const int n = tid - 64;
      const float s = f2p[n][0] + f2p[n][1] + f2p[n][2] + f2p[n][3];
      f2g[b*1024 + (ms*32 + n)*4 + nt] = s;
    }
  }

  __threadfence();
  cg::this_grid().sync();

  // ================= phase 2: attn (blk -> b, hp, it2) =====================
  {
    const int it2 = blk & 7, hp = (blk >> 3) & 3, b = blk >> 5;
    const int i0 = it2 * 32;
    const int rt = wv >> 2, ct = wv & 3;

    // ---- prefetch everything global this block needs ----------------------
    bf16x8 bv[8];                                  // WhT B-frags (K=256)
    const short* bp = WhT + b*65536 + (hp*64 + ct*16 + col)*256 + quad*8;
#pragma unroll
    for (int kk = 0; kk < 8; kk++) bv[kk] = *(const bf16x8*)(bp + kk*32);

    float4 f2v[4]; int4 av[4]; float f1s[4];
#pragma unroll
    for (int rq = 0; rq < 4; rq++) {
      const int i = i0 + wv*4 + rq;                // i & 3 == rq
      f2v[rq] = *(const float4*)(f2g + b*1024 + rq*256 + lane*4);
      av[rq]  = *(const int4*)(adj + (b*256 + i)*256 + lane*4);
      f1s[rq] = f1g[b*1024 + hp*256 + i];
    }

    // ---- softmax numerators only (no max-sub, no reductions at all) -------
#pragma unroll
    for (int rq = 0; rq < 4; rq++) {
      const int rr = wv*4 + rq;
      const float s1v = f1s[rq];
      float e0 = s1v + f2v[rq].x, e1 = s1v + f2v[rq].y;
      float e2 = s1v + f2v[rq].z, e3 = s1v + f2v[rq].w;
      e0 = e0 > 0.f ? e0 : 0.2f*e0;  e1 = e1 > 0.f ? e1 : 0.2f*e1;
      e2 = e2 > 0.f ? e2 : 0.2f*e2;  e3 = e3 > 0.f ? e3 : 0.2f*e3;
      e0 = av[rq].x ? e0 : -1e30f;  e1 = av[rq].y ? e1 : -1e30f;
      e2 = av[rq].z ? e2 : -1e30f;  e3 = av[rq].w ? e3 : -1e30f;
      float x0 = __expf(e0), x1 = __expf(e1);
      float x2 = __expf(e2), x3 = __expf(e3);
      int2 pk2;
      pk2.x = (int)((unsigned)(unsigned short)bf1(x0) |
                    ((unsigned)(unsigned short)bf1(x1) << 16));
      pk2.y = (int)((unsigned)(unsigned short)bf1(x2) |
                    ((unsigned)(unsigned short)bf1(x3) << 16));
      *(int2*)&attb[rr][lane*4] = pk2;
    }
    __syncthreads();

    // ---- GEMM + MFMA row-sums: wave (rt,ct) -------------------------------
    bf16x8 af[8];
#pragma unroll
    for (int kk = 0; kk < 8; kk++)
      af[kk] = *(const bf16x8*)&attb[rt*16 + col][kk*32 + quad*8];

    bf16x8 ones;
#pragma unroll
    for (int j = 0; j < 8; j++) ones[j] = (short)0x3F80;   // bf16 1.0

    f32x4 acc0 = {0.f,0.f,0.f,0.f}, acc1 = {0.f,0.f,0.f,0.f};
    f32x4 sum0 = {0.f,0.f,0.f,0.f}, sum1 = {0.f,0.f,0.f,0.f};
#pragma unroll
    for (int kk = 0; kk < 4; kk++) {
      acc0 = __builtin_amdgcn_mfma_f32_16x16x32_bf16(af[kk],   bv[kk],   acc0, 0, 0, 0);
      acc1 = __builtin_amdgcn_mfma_f32_16x16x32_bf16(af[kk+4], bv[kk+4], acc1, 0, 0, 0);
      sum0 = __builtin_amdgcn_mfma_f32_16x16x32_bf16(af[kk],   ones,     sum0, 0, 0, 0);
      sum1 = __builtin_amdgcn_mfma_f32_16x16x32_bf16(af[kk+4], ones,     sum1, 0, 0, 0);
    }
#pragma unroll
    for (int r = 0; r < 4; r++) {
      const int m = rt*16 + quad*4 + r;            // row within 32-tile
      out[(b*256 + i0 + m)*256 + hp*64 + ct*16 + col] =
          (acc0[r] + acc1[r]) / (sum0[r] + sum1[r]);
    }
  }
}

extern "C" void kernel_launch(void* const* d_in, const int* in_sizes, int n_in,
                              void* d_out, int out_size, void* d_ws, size_t ws_size,
                              hipStream_t stream) {
  const float* h   = (const float*)d_in[0];   // [4,256,128]
  const int*   adj = (const int*)d_in[1];     // [4,256,256]
  const float* W   = (const float*)d_in[2];   // [128,256]
  const float* a   = (const float*)d_in[3];   // [128,1]
  float* out = (float*)d_out;                 // [4,256,256]

  short* WhT = (short*)d_ws;                  // [4][256 dcol][256 n] bf16, 512 KB
  float* f1g = (float*)((char*)d_ws + 4*256*256*2);   // [4][1024] f32
  float* f2g = f1g + 4*1024;                           // [4][1024] f32

  void* args[] = { (void*)&h, (void*)&W, (void*)&a, (void*)&adj,
                   (void*)&WhT, (void*)&f1g, (void*)&f2g, (void*)&out };
  hipLaunchCooperativeKernel(gat_all, dim3(128), dim3(512), args, 0, stream);
}

// Round 6
// 64.076 us; speedup vs baseline: 1.6768x; 1.6768x over previous
//
#include <hip/hip_runtime.h>

// GAT layer, B=4, N=256, IN=128, H=4, D=64 — two plain kernels (R13).
//
// out = att @ (h@W)slice.  Kernel A: Wh^T bf16 + f1/f2 attention vectors.
// Kernel B: masked softmax + one K=256 MFMA GEMM; softmax denominator via
// MFMA against a ones-fragment (no cross-lane reduce at all in B).
//
// R6 changes (R5 post-mortem: cooperative launch = +38us machinery, revert;
// R2 showed instruction count is NOT the bottleneck -> latency/parallelism):
//  - both kernels regridded 128x512 -> 256x256: ALL 256 CUs active, per-block
//    critical path halved (16-row strips/tiles).
//  - kernel B keeps the R5 MFMA row-sum (harness-verified absmax 0.00195):
//    denominator sums the same bf16-rounded attb the numerator uses.
//  - no max-subtraction in softmax (R4-verified: |e| small, exp(-1e30)=0).
//
// Index algebra (harness-verified R0/R3/R4/R5):
//   e[b,hp,i,j] = lrelu_0.2( f1flat[hp*256+i] + f2flat[(i&3)*256+j] ), flat=n*4+hh
//   att = softmax_j(adj==0 ? -inf : e);  out = (attU @ Wh[:,hp*64:+64]) / rowsum

typedef __attribute__((ext_vector_type(8))) short bf16x8;
typedef __attribute__((ext_vector_type(4))) float f32x4;

__device__ __forceinline__ short bf1(float x) {
  unsigned u = __builtin_bit_cast(unsigned, x);
  u = (u + 0x7FFFu + ((u >> 16) & 1u)) >> 16;        // RNE, harness-verified
  return (short)u;
}
__device__ __forceinline__ bf16x8 pack8(float4 a, float4 b) {
  bf16x8 r;
  r[0]=bf1(a.x); r[1]=bf1(a.y); r[2]=bf1(a.z); r[3]=bf1(a.w);
  r[4]=bf1(b.x); r[5]=bf1(b.y); r[6]=bf1(b.z); r[7]=bf1(b.w);
  return r;
}

// ---------------- Kernel A: Wh + f1/f2 ------------------------------------
// grid 256 = (4b x 4nt x 16ms); block (256 thr, 4 waves) computes
// Wh[b][ms*16:+16][nt*64:+64]; wave wv owns col-tile tc=wv.
__global__ __launch_bounds__(256) void gat_prep(
    const float* __restrict__ h, const float* __restrict__ W,
    const float* __restrict__ a,
    short* __restrict__ WhT, float* __restrict__ f1g, float* __restrict__ f2g)
{
  const int tid  = threadIdx.x;
  const int lane = tid & 63;
  const int quad = lane >> 4, col = lane & 15;
  const int wv   = tid >> 6;                       // 0..3 == col-tile tc
  const int blk  = blockIdx.x;
  const int ms = blk & 15, nt = (blk >> 4) & 3, b = blk >> 6;

  __shared__ short WbT[64][136];     // bf16 W[:, nt*64:+64]^T : [c][k]
  __shared__ float f1p[16][4];       // per-row partial dots, by tc
  __shared__ float f2p[16][4];

  // ---- issue ALL global loads first (HBM latency overlaps staging) --------
  float4 wl[8];
#pragma unroll
  for (int q = 0; q < 8; q++) {
    const int idx = q * 256 + tid;                 // 2048 float4 of W slice
    const int k = idx >> 4, c4 = idx & 15;
    wl[q] = *(const float4*)(W + k * 256 + nt * 64 + c4 * 4);
  }
  const float* hrow = h + (b*256 + ms*16 + col) * 128 + quad*8;
  float4 hv[8];
#pragma unroll
  for (int kk = 0; kk < 4; kk++) {
    hv[2*kk]   = *(const float4*)(hrow + kk*32);
    hv[2*kk+1] = *(const float4*)(hrow + kk*32 + 4);
  }
  const float a1v = a[wv*16 + col];
  const float a2v = a[64 + wv*16 + col];

  // ---- stage WbT -----------------------------------------------------------
#pragma unroll
  for (int q = 0; q < 8; q++) {
    const int idx = q * 256 + tid;
    const int k = idx >> 4, c4 = idx & 15;
    WbT[c4*4 + 0][k] = bf1(wl[q].x);
    WbT[c4*4 + 1][k] = bf1(wl[q].y);
    WbT[c4*4 + 2][k] = bf1(wl[q].z);
    WbT[c4*4 + 3][k] = bf1(wl[q].w);
  }
  __syncthreads();

  // ---- MFMA: Wh tile (16x16), K=128 ---------------------------------------
  f32x4 acc = {0.f, 0.f, 0.f, 0.f};
#pragma unroll
  for (int kk = 0; kk < 4; kk++) {
    bf16x8 bw = *(const bf16x8*)&WbT[wv*16 + col][kk*32 + quad*8];
    acc = __builtin_amdgcn_mfma_f32_16x16x32_bf16(pack8(hv[2*kk], hv[2*kk+1]), bw, acc, 0, 0, 0);
  }
  // acc[r] = Wh[b][ms*16+quad*4+r][nt*64+wv*16+col]
  {
    const int dcol = nt*64 + wv*16 + col;
    const int n0   = ms*16 + quad*4;
    int2 pk;
    pk.x = (int)((unsigned)(unsigned short)bf1(acc[0]) |
                 ((unsigned)(unsigned short)bf1(acc[1]) << 16));
    pk.y = (int)((unsigned)(unsigned short)bf1(acc[2]) |
                 ((unsigned)(unsigned short)bf1(acc[3]) << 16));
    *(int2*)(WhT + b*65536 + dcol*256 + n0) = pk;
  }
  // ---- f1/f2 partials: reduce acc[r]*a over this 16-col tile --------------
#pragma unroll
  for (int r = 0; r < 4; r++) {
    float v1 = acc[r] * a1v;
    float v2 = acc[r] * a2v;
#pragma unroll
    for (int off = 1; off < 16; off <<= 1) {
      v1 += __shfl_xor(v1, off, 64);
      v2 += __shfl_xor(v2, off, 64);
    }
    if (col == 0) {
      const int row = quad*4 + r;                  // 0..15 within strip
      f1p[row][wv] = v1;
      f2p[row][wv] = v2;
    }
  }
  __syncthreads();

  // finalize: sum the 4 tc partials, write f{1,2}flat[b][(ms*16+n)*4 + nt]
  if (tid < 16) {
    const float s = f1p[tid][0] + f1p[tid][1] + f1p[tid][2] + f1p[tid][3];
    f1g[b*1024 + (ms*16 + tid)*4 + nt] = s;
  } else if (tid >= 64 && tid < 80) {
    const int n = tid - 64;
    const float s = f2p[n][0] + f2p[n][1] + f2p[n][2] + f2p[n][3];
    f2g[b*1024 + (ms*16 + n)*4 + nt] = s;
  }
}

// ---------------- Kernel B: softmax + att @ Wh-slice ----------------------
// grid 256 = (4b x 4hp x 16 tiles of 16 rows); 256 threads, 4 waves.
// wave wv: softmax rows wv*4..+3, GEMM col-tile ct=wv.
__global__ __launch_bounds__(256) void gat_attn(
    const short* __restrict__ WhT, const float* __restrict__ f1g,
    const float* __restrict__ f2g, const int* __restrict__ adj,
    float* __restrict__ out)
{
  const int tid  = threadIdx.x;
  const int lane = tid & 63;
  const int quad = lane >> 4, col = lane & 15;
  const int wv   = tid >> 6;                       // 0..3 == col-tile ct
  const int blk  = blockIdx.x;
  const int it = blk & 15, hp = (blk >> 4) & 3, b = blk >> 6;
  const int i0 = it * 16;

  __shared__ short attb[16][264];    // bf16 unnormalized softmax rows

  // ---- prefetch everything global this block needs -------------------------
  bf16x8 bv[8];                                    // WhT B-frags (K=256)
  const short* bp = WhT + b*65536 + (hp*64 + wv*16 + col)*256 + quad*8;
#pragma unroll
  for (int kk = 0; kk < 8; kk++) bv[kk] = *(const bf16x8*)(bp + kk*32);

  float4 f2v[4]; int4 av[4]; float f1s[4];
#pragma unroll
  for (int rq = 0; rq < 4; rq++) {
    const int i = i0 + wv*4 + rq;                  // i & 3 == rq
    f2v[rq] = *(const float4*)(f2g + b*1024 + rq*256 + lane*4);
    av[rq]  = *(const int4*)(adj + (b*256 + i)*256 + lane*4);
    f1s[rq] = f1g[b*1024 + hp*256 + i];
  }

  // ---- softmax numerators only (no reductions at all) ----------------------
#pragma unroll
  for (int rq = 0; rq < 4; rq++) {
    const int rr = wv*4 + rq;
    const float s1v = f1s[rq];
    float e0 = s1v + f2v[rq].x, e1 = s1v + f2v[rq].y;
    float e2 = s1v + f2v[rq].z, e3 = s1v + f2v[rq].w;
    e0 = e0 > 0.f ? e0 : 0.2f*e0;  e1 = e1 > 0.f ? e1 : 0.2f*e1;
    e2 = e2 > 0.f ? e2 : 0.2f*e2;  e3 = e3 > 0.f ? e3 : 0.2f*e3;
    e0 = av[rq].x ? e0 : -1e30f;  e1 = av[rq].y ? e1 : -1e30f;
    e2 = av[rq].z ? e2 : -1e30f;  e3 = av[rq].w ? e3 : -1e30f;
    float x0 = __expf(e0), x1 = __expf(e1);
    float x2 = __expf(e2), x3 = __expf(e3);
    int2 pk2;
    pk2.x = (int)((unsigned)(unsigned short)bf1(x0) |
                  ((unsigned)(unsigned short)bf1(x1) << 16));
    pk2.y = (int)((unsigned)(unsigned short)bf1(x2) |
                  ((unsigned)(unsigned short)bf1(x3) << 16));
    *(int2*)&attb[rr][lane*4] = pk2;
  }
  __syncthreads();

  // ---- GEMM + MFMA row-sums ------------------------------------------------
  bf16x8 af[8];
#pragma unroll
  for (int kk = 0; kk < 8; kk++)
    af[kk] = *(const bf16x8*)&attb[col][kk*32 + quad*8];

  bf16x8 ones;
#pragma unroll
  for (int j = 0; j < 8; j++) ones[j] = (short)0x3F80;   // bf16 1.0

  f32x4 acc0 = {0.f,0.f,0.f,0.f}, acc1 = {0.f,0.f,0.f,0.f};
  f32x4 sum0 = {0.f,0.f,0.f,0.f}, sum1 = {0.f,0.f,0.f,0.f};
#pragma unroll
  for (int kk = 0; kk < 4; kk++) {
    acc0 = __builtin_amdgcn_mfma_f32_16x16x32_bf16(af[kk],   bv[kk],   acc0, 0, 0, 0);
    acc1 = __builtin_amdgcn_mfma_f32_16x16x32_bf16(af[kk+4], bv[kk+4], acc1, 0, 0, 0);
    sum0 = __builtin_amdgcn_mfma_f32_16x16x32_bf16(af[kk],   ones,     sum0, 0, 0, 0);
    sum1 = __builtin_amdgcn_mfma_f32_16x16x32_bf16(af[kk+4], ones,     sum1, 0, 0, 0);
  }
#pragma unroll
  for (int r = 0; r < 4; r++) {
    const int m = quad*4 + r;                      // row within 16-tile
    out[(b*256 + i0 + m)*256 + hp*64 + wv*16 + col] =
        (acc0[r] + acc1[r]) / (sum0[r] + sum1[r]);
  }
}

extern "C" void kernel_launch(void* const* d_in, const int* in_sizes, int n_in,
                              void* d_out, int out_size, void* d_ws, size_t ws_size,
                              hipStream_t stream) {
  const float* h   = (const float*)d_in[0];   // [4,256,128]
  const int*   adj = (const int*)d_in[1];     // [4,256,256]
  const float* W   = (const float*)d_in[2];   // [128,256]
  const float* a   = (const float*)d_in[3];   // [128,1]
  float* out = (float*)d_out;                 // [4,256,256]

  short* WhT = (short*)d_ws;                  // [4][256 dcol][256 n] bf16, 512 KB
  float* f1g = (float*)((char*)d_ws + 4*256*256*2);   // [4][1024] f32
  float* f2g = f1g + 4*1024;                           // [4][1024] f32

  gat_prep<<<256, 256, 0, stream>>>(h, W, a, WhT, f1g, f2g);
  gat_attn<<<256, 256, 0, stream>>>(WhT, f1g, f2g, adj, out);
}